// Round 1
// baseline (1898.467 us; speedup 1.0000x reference)
//
#include <hip/hip_runtime.h>
#include <hip/hip_bf16.h>

// QLSTM: T=512, B=256, D=128, H=256.  z = [x,h] @ W^T + b, W=[4H, D+H]=[1024,384]
// Round 0 design: one kernel launch per timestep (stream order = global sync).
// Block = (16 batches) x (16 hidden units) x all 4 gates; wave g computes gate g's
// 16x16x384 MFMA tile; gates combined via small LDS exchange; h stored bf16 into
// hs[t+1]. Epilogue: probs = sigmoid(hs @ Wc^T + bc), plus hx/cx outputs.

#define T_STEPS 512
#define BATCH   256
#define DIN     128
#define HID     256
#define KDIM    384   // DIN + HID
#define NDIM    1024  // 4*HID
#define LDK     392   // padded LDS row stride (elements) to break bank conflicts

typedef __attribute__((ext_vector_type(8))) short short8;
typedef __attribute__((ext_vector_type(4))) short short4v;
typedef __attribute__((ext_vector_type(4))) float f32x4;

__device__ __forceinline__ unsigned short f2bf(float f) {
    unsigned u = __float_as_uint(f);
    unsigned r = (u + 0x7FFFu + ((u >> 16) & 1u)) >> 16;
    return (unsigned short)r;
}
__device__ __forceinline__ float bf2f(unsigned short s) {
    return __uint_as_float(((unsigned)s) << 16);
}

// ---- pack weights: Wpack[n][k] bf16, n = g*256 + j, row-major [1024][384] ----
__global__ __launch_bounds__(256) void pack_w(
    const float* __restrict__ Wf, const float* __restrict__ Wi,
    const float* __restrict__ Wg, const float* __restrict__ Wo,
    unsigned short* __restrict__ Wp) {
    int idx = blockIdx.x * 256 + threadIdx.x;        // < 1024*384
    int n = idx / KDIM;
    int k = idx - n * KDIM;
    int g = n >> 8, j = n & 255;
    const float* s = (g == 0) ? Wf : (g == 1) ? Wi : (g == 2) ? Wg : Wo;
    Wp[idx] = f2bf(s[j * KDIM + k]);
}

__global__ __launch_bounds__(256) void pack_b(
    const float* __restrict__ bf, const float* __restrict__ bi,
    const float* __restrict__ bg, const float* __restrict__ bo,
    float* __restrict__ bp) {
    int n = blockIdx.x * 256 + threadIdx.x;          // < 1024
    int g = n >> 8, j = n & 255;
    const float* s = (g == 0) ? bf : (g == 1) ? bi : (g == 2) ? bg : bo;
    bp[n] = s[j];
}

// ---- zero h0 (bf16) and c0 (fp32) ----
__global__ __launch_bounds__(256) void init_state(
    unsigned short* __restrict__ hs, float* __restrict__ cx) {
    int tid = blockIdx.x * 256 + threadIdx.x;        // < 65536
    hs[tid] = 0;
    cx[tid] = 0.f;
}

// ---- one LSTM step ----
// grid (16,16): blockIdx.x = batch group (16 rows), blockIdx.y = hidden-unit group (16 j's)
// 256 threads = 4 waves; wave w owns gate w.
__global__ __launch_bounds__(256) void lstm_step(
    const float* __restrict__ X,            // [T,B,D] fp32
    const unsigned short* __restrict__ W,   // [1024][384] bf16
    const float* __restrict__ bias,         // [1024]
    unsigned short* __restrict__ hs,        // [T+1][B][H] bf16
    float* __restrict__ cx,                 // [B][H] fp32
    int t) {
    __shared__ __align__(16) unsigned short W_s[64 * LDK];    // 50176 B
    __shared__ __align__(16) unsigned short comb_s[16 * LDK]; // 12544 B (z overlay later)

    const int tid = threadIdx.x;
    const int b0 = blockIdx.x * 16;
    const int j0 = blockIdx.y * 16;

    // stage W tile: local row = g*16 + jj  <-  global row g*256 + j0 + jj ; 64x384 bf16
#pragma unroll
    for (int c = 0; c < 12; ++c) {
        int q = c * 256 + tid;               // 0..3071 ushort8 chunks
        int row = q / 48, c8 = q - row * 48; // 48 chunks of 8 per row
        int g = row >> 4, jj = row & 15;
        short8 v = *(const short8*)(W + ((g * 256 + j0 + jj) * KDIM + c8 * 8));
        *(short8*)(&W_s[row * LDK + c8 * 8]) = v;
    }
    // stage combined: cols [0,128) = x_t (fp32 -> bf16), [128,384) = h_{t-1} (bf16)
    const float* xbase = X + (size_t)t * BATCH * DIN;
#pragma unroll
    for (int c = 0; c < 2; ++c) {
        int q = c * 256 + tid;               // 0..511 float4 chunks
        int row = q >> 5, c4 = q & 31;
        const float4 v = *(const float4*)(xbase + (b0 + row) * DIN + c4 * 4);
        short4v r;
        r.x = (short)f2bf(v.x); r.y = (short)f2bf(v.y);
        r.z = (short)f2bf(v.z); r.w = (short)f2bf(v.w);
        *(short4v*)(&comb_s[row * LDK + c4 * 4]) = r;
    }
    const unsigned short* hprev = hs + (size_t)t * BATCH * HID;
#pragma unroll
    for (int c = 0; c < 2; ++c) {
        int q = c * 256 + tid;               // 0..511 ushort8 chunks
        int row = q >> 5, c8 = q & 31;
        short8 v = *(const short8*)(hprev + (b0 + row) * HID + c8 * 8);
        *(short8*)(&comb_s[row * LDK + DIN + c8 * 8]) = v;
    }
    __syncthreads();

    // MFMA: wave computes z_g = comb[16 x 384] * W_g^T[384 x 16]
    const int wave = tid >> 6;
    const int lane = tid & 63;
    const int l16 = lane & 15, quad = lane >> 4;
    f32x4 acc = {0.f, 0.f, 0.f, 0.f};
    const unsigned short* arow = &comb_s[l16 * LDK + quad * 8];
    const unsigned short* brow = &W_s[(wave * 16 + l16) * LDK + quad * 8];
#pragma unroll
    for (int kt = 0; kt < 12; ++kt) {
        short8 a = *(const short8*)(arow + kt * 32);
        short8 b = *(const short8*)(brow + kt * 32);
        acc = __builtin_amdgcn_mfma_f32_16x16x32_bf16(a, b, acc, 0, 0, 0);
    }
    __syncthreads();               // everyone done reading comb_s
    float* z_s = (float*)comb_s;   // overlay: [4 gates][16 rows][16 cols] fp32 = 4 KB
#pragma unroll
    for (int r = 0; r < 4; ++r)
        z_s[wave * 256 + (quad * 4 + r) * 16 + l16] = acc[r];
    __syncthreads();

    // elementwise: thread owns (bi, jj)
    const int bi = tid >> 4, jj = tid & 15;
    const int b = b0 + bi, j = j0 + jj;
    float zf = z_s[0 * 256 + bi * 16 + jj] + bias[0 * 256 + j];
    float zi = z_s[1 * 256 + bi * 16 + jj] + bias[1 * 256 + j];
    float zg = z_s[2 * 256 + bi * 16 + jj] + bias[2 * 256 + j];
    float zo = z_s[3 * 256 + bi * 16 + jj] + bias[3 * 256 + j];
    float fg = 1.f / (1.f + expf(-zf));
    float ig = 1.f / (1.f + expf(-zi));
    float gg = tanhf(zg);
    float og = 1.f / (1.f + expf(-zo));
    float c_old = cx[b * HID + j];
    float c_new = fg * c_old + ig * gg;
    cx[b * HID + j] = c_new;
    float h = og * tanhf(c_new);
    hs[(size_t)(t + 1) * BATCH * HID + b * HID + j] = f2bf(h);
}

// ---- classifier head: one wave per (t,b) row ----
__global__ __launch_bounds__(256) void probs_k(
    const unsigned short* __restrict__ hs, const float* __restrict__ Wc,
    const float* __restrict__ bc, float* __restrict__ out) {
    const int wave = threadIdx.x >> 6, lane = threadIdx.x & 63;
    const size_t row = (size_t)blockIdx.x * 4 + wave;   // row = t*256 + b, < 131072
    const unsigned short* h = hs + (size_t)BATCH * HID + row * HID; // hs[t+1][b][:]
    short4v hv = *(const short4v*)(h + lane * 4);
    const float4 wv = *(const float4*)(Wc + lane * 4);
    float p = bf2f((unsigned short)hv.x) * wv.x + bf2f((unsigned short)hv.y) * wv.y +
              bf2f((unsigned short)hv.z) * wv.z + bf2f((unsigned short)hv.w) * wv.w;
#pragma unroll
    for (int off = 32; off >= 1; off >>= 1) p += __shfl_down(p, off);
    if (lane == 0) {
        float prob = 1.f / (1.f + expf(-(p + bc[0])));
        out[row * 2]     = prob;
        out[row * 2 + 1] = 1.f - prob;
    }
}

// ---- hx (bf16 -> fp32) and cx outputs ----
__global__ __launch_bounds__(256) void tail_k(
    const unsigned short* __restrict__ hs, const float* __restrict__ cx,
    float* __restrict__ out) {
    int tid = blockIdx.x * 256 + threadIdx.x;           // < 65536
    out[T_STEPS * BATCH * 2 + tid] = bf2f(hs[(size_t)T_STEPS * BATCH * HID + tid]);
    out[T_STEPS * BATCH * 2 + BATCH * HID + tid] = cx[tid];
}

extern "C" void kernel_launch(void* const* d_in, const int* in_sizes, int n_in,
                              void* d_out, int out_size, void* d_ws, size_t ws_size,
                              hipStream_t stream) {
    const float* X  = (const float*)d_in[0];
    const float* Wf = (const float*)d_in[1];
    const float* bf = (const float*)d_in[2];
    const float* Wi = (const float*)d_in[3];
    const float* bi = (const float*)d_in[4];
    const float* Wg = (const float*)d_in[5];
    const float* bg = (const float*)d_in[6];
    const float* Wo = (const float*)d_in[7];
    const float* bo = (const float*)d_in[8];
    const float* Wc = (const float*)d_in[9];
    const float* bc = (const float*)d_in[10];
    float* out = (float*)d_out;

    char* ws = (char*)d_ws;
    unsigned short* Wpack = (unsigned short*)(ws);               // 786432 B
    float* bias = (float*)(ws + 786432);                         // 4096 B
    float* cx   = (float*)(ws + 790528);                         // 262144 B
    unsigned short* hs = (unsigned short*)(ws + 1052672);        // (T+1)*B*H*2 = 67239936 B

    pack_w<<<1536, 256, 0, stream>>>(Wf, Wi, Wg, Wo, Wpack);
    pack_b<<<4, 256, 0, stream>>>(bf, bi, bg, bo, bias);
    init_state<<<256, 256, 0, stream>>>(hs, cx);
    for (int t = 0; t < T_STEPS; ++t)
        lstm_step<<<dim3(16, 16), 256, 0, stream>>>(X, Wpack, bias, hs, cx, t);
    probs_k<<<32768, 256, 0, stream>>>(hs, Wc, bc, out);
    tail_k<<<256, 256, 0, stream>>>(hs, cx, out);
}